// Round 1
// baseline (478.419 us; speedup 1.0000x reference)
//
#include <hip/hip_runtime.h>

// Problem constants (fixed by setup_inputs)
constexpr int B = 4, N = 2048, I = 256, H = 4, D = 64, E = 256; // E = H*D

// ---------------- Kernel 1: per-head projection + H1/H2 ----------------
// Hp[b][h][n][d] = sum_i X[b][n][i] * W[h][i][d]
// H1[b][h][n] = dot(Hp[b,h,n,:], a[h, 0:D]); H2 with a[h, D:2D]
constexpr int NT = 8; // nodes per block

__global__ __launch_bounds__(256) void k_proj(const float* __restrict__ X,
                                              const float* __restrict__ W,
                                              const float* __restrict__ a,
                                              float* __restrict__ Hp,
                                              float* __restrict__ H1,
                                              float* __restrict__ H2) {
    int blk = blockIdx.x;
    int b = blk / (N / NT);
    int n0 = (blk % (N / NT)) * NT;
    int t = threadIdx.x;
    int h = t >> 6, d = t & 63;

    __shared__ float Xs[NT][I]; // 8 KB

    const float4* Xr = (const float4*)(X + ((size_t)b * N + n0) * I);
    #pragma unroll
    for (int k = 0; k < (NT * I / 4) / 256; ++k) { // 2 iters
        int v = t + 256 * k;
        ((float4*)&Xs[0][0])[v] = Xr[v];
    }
    __syncthreads();

    float acc[NT];
    #pragma unroll
    for (int nn = 0; nn < NT; ++nn) acc[nn] = 0.f;

    const float* Wp = W + (size_t)h * I * D + d;
    #pragma unroll 2
    for (int i4 = 0; i4 < I; i4 += 4) {
        float w0 = Wp[(size_t)(i4 + 0) * D];
        float w1 = Wp[(size_t)(i4 + 1) * D];
        float w2 = Wp[(size_t)(i4 + 2) * D];
        float w3 = Wp[(size_t)(i4 + 3) * D];
        #pragma unroll
        for (int nn = 0; nn < NT; ++nn) {
            float4 x = *(const float4*)&Xs[nn][i4];
            acc[nn] += x.x * w0 + x.y * w1 + x.z * w2 + x.w * w3;
        }
    }

    float a1 = a[h * (2 * D) + d];
    float a2 = a[h * (2 * D) + D + d];

    #pragma unroll
    for (int nn = 0; nn < NT; ++nn) {
        size_t idx = ((size_t)(b * H + h) * N + (n0 + nn)) * D + d;
        Hp[idx] = acc[nn];
        float v1 = acc[nn] * a1;
        float v2 = acc[nn] * a2;
        #pragma unroll
        for (int off = 32; off > 0; off >>= 1) {
            v1 += __shfl_down(v1, off, 64);
            v2 += __shfl_down(v2, off, 64);
        }
        if (d == 0) {
            H1[(size_t)(b * H + h) * N + (n0 + nn)] = v1;
            H2[(size_t)(b * H + h) * N + (n0 + nn)] = v2;
        }
    }
}

// ---------------- Kernel 2: head-softmax weighted aggregation ----------------
// w[h](i,j) = softmax over h of lrelu(H1[h,i]+H2[h,j]) if A[i,j]>0 else 0.25
// Hprime[b][h][i][d] = sum_j w[h](i,j) * Hp[b][h][j][d]
constexpr int IT = 16; // i rows per block
constexpr int JT = 64; // j tile

__global__ __launch_bounds__(256) void k_agg(const int* __restrict__ A,
                                             const float* __restrict__ Hp,
                                             const float* __restrict__ H1,
                                             const float* __restrict__ H2,
                                             float* __restrict__ Hpr) {
    int b = blockIdx.x / (N / IT);
    int i0 = (blockIdx.x % (N / IT)) * IT;
    int t = threadIdx.x;
    int h = t >> 6, d = t & 63;

    __shared__ float wls[H][IT][JT]; // 16 KB
    __shared__ float H1s[H][IT];     // 256 B

    if (t < H * IT) {
        int hh = t >> 4, ii = t & 15;
        H1s[hh][ii] = H1[(size_t)(b * H + hh) * N + i0 + ii];
    }

    float acc[IT];
    #pragma unroll
    for (int i = 0; i < IT; ++i) acc[i] = 0.f;

    const float* Hpb = Hp + ((size_t)(b * H + h) * N) * D + d;
    const float* H2b = H2 + (size_t)b * H * N;
    const int*   Ab  = A + (size_t)b * N * N;

    for (int j0 = 0; j0 < N; j0 += JT) {
        __syncthreads(); // protect wls (prev Phase B) and H1s (first iter)

        // ---- Phase A: weights for IT*JT pairs, 4 pairs per thread ----
        #pragma unroll
        for (int r = 0; r < (IT * JT) / 256; ++r) { // 4
            int p = t + 256 * r;
            int i = p >> 6;   // p / JT
            int j = p & 63;   // p % JT
            int aij = Ab[(size_t)(i0 + i) * N + j0 + j];
            float w0, w1, w2, w3;
            if (aij > 0) {
                float s0 = H1s[0][i] + H2b[0 * N + j0 + j];
                float s1 = H1s[1][i] + H2b[1 * N + j0 + j];
                float s2 = H1s[2][i] + H2b[2 * N + j0 + j];
                float s3 = H1s[3][i] + H2b[3 * N + j0 + j];
                s0 = s0 > 0.f ? s0 : 0.2f * s0;
                s1 = s1 > 0.f ? s1 : 0.2f * s1;
                s2 = s2 > 0.f ? s2 : 0.2f * s2;
                s3 = s3 > 0.f ? s3 : 0.2f * s3;
                float m = fmaxf(fmaxf(s0, s1), fmaxf(s2, s3));
                float e0 = __expf(s0 - m);
                float e1 = __expf(s1 - m);
                float e2 = __expf(s2 - m);
                float e3 = __expf(s3 - m);
                float zinv = 1.f / (e0 + e1 + e2 + e3);
                w0 = e0 * zinv; w1 = e1 * zinv; w2 = e2 * zinv; w3 = e3 * zinv;
            } else {
                w0 = w1 = w2 = w3 = 0.25f;
            }
            wls[0][i][j] = w0;
            wls[1][i][j] = w1;
            wls[2][i][j] = w2;
            wls[3][i][j] = w3;
        }
        __syncthreads();

        // ---- Phase B: acc[i] += w[h][i][j] * Hp[b][h][j][d] ----
        const float* hj = Hpb + (size_t)j0 * D;
        #pragma unroll 4
        for (int jg = 0; jg < JT / 4; ++jg) {
            float hp0 = hj[(size_t)(jg * 4 + 0) * D];
            float hp1 = hj[(size_t)(jg * 4 + 1) * D];
            float hp2 = hj[(size_t)(jg * 4 + 2) * D];
            float hp3 = hj[(size_t)(jg * 4 + 3) * D];
            #pragma unroll
            for (int i = 0; i < IT; ++i) {
                float4 w = *(const float4*)&wls[h][i][jg * 4];
                acc[i] += w.x * hp0 + w.y * hp1 + w.z * hp2 + w.w * hp3;
            }
        }
    }

    #pragma unroll
    for (int i = 0; i < IT; ++i) {
        Hpr[((size_t)(b * H + h) * N + i0 + i) * D + d] = acc[i];
    }
}

// ---------------- Kernel 3: output GEMM out = R @ W_out^T + b_out ----------------
// R (reshape view) flat == Hpr flat viewed as [B*N][E]
constexpr int R3 = 16; // rows per block
constexpr int ET = 32; // e' tile

__global__ __launch_bounds__(256) void k_out(const float* __restrict__ Hpr,
                                             const float* __restrict__ Wo,
                                             const float* __restrict__ bo,
                                             float* __restrict__ out) {
    int row0 = blockIdx.x * R3; // global row = b*N + n'
    int t = threadIdx.x;        // e

    __shared__ float Rs[R3][E];       // 16 KB
    __shared__ float WT[ET][E + 1];   // 32.1 KB, transposed W_out tile [e'][e]

    // stage R rows (contiguous)
    const float4* src = (const float4*)(Hpr + (size_t)row0 * E);
    #pragma unroll
    for (int k = 0; k < (R3 * E / 4) / 256; ++k) { // 4
        int v = t + 256 * k;
        ((float4*)&Rs[0][0])[v] = src[v];
    }

    float acc[R3];
    float bias = bo[t];
    #pragma unroll
    for (int i = 0; i < R3; ++i) acc[i] = bias;

    for (int et = 0; et < E / ET; ++et) { // 8 tiles
        __syncthreads(); // protect WT (prev compute), Rs ready (first iter)
        // stage W_out[:, et*32 .. +32) transposed: 8192 elems, 32 per thread
        int c_l = t & 31;
        int rbase = t >> 5;
        #pragma unroll 8
        for (int k = 0; k < 32; ++k) {
            int r = rbase + 8 * k;
            WT[c_l][r] = Wo[(size_t)r * E + et * ET + c_l];
        }
        __syncthreads();

        #pragma unroll 4
        for (int cg = 0; cg < ET / 4; ++cg) {
            float w0 = WT[cg * 4 + 0][t];
            float w1 = WT[cg * 4 + 1][t];
            float w2 = WT[cg * 4 + 2][t];
            float w3 = WT[cg * 4 + 3][t];
            #pragma unroll
            for (int i = 0; i < R3; ++i) {
                float4 rv = *(const float4*)&Rs[i][et * ET + cg * 4];
                acc[i] += rv.x * w0 + rv.y * w1 + rv.z * w2 + rv.w * w3;
            }
        }
    }

    #pragma unroll
    for (int i = 0; i < R3; ++i) {
        out[(size_t)(row0 + i) * E + t] = acc[i];
    }
}

extern "C" void kernel_launch(void* const* d_in, const int* in_sizes, int n_in,
                              void* d_out, int out_size, void* d_ws, size_t ws_size,
                              hipStream_t stream) {
    const float* X  = (const float*)d_in[0];
    const int*   A  = (const int*)d_in[1];
    const float* W  = (const float*)d_in[2];
    const float* a  = (const float*)d_in[3];
    const float* Wo = (const float*)d_in[4];
    const float* bo = (const float*)d_in[5];
    float* out = (float*)d_out;

    float* ws  = (float*)d_ws;
    float* Hp  = ws;                      // B*H*N*D = 2,097,152 floats
    float* Hpr = ws + 2097152;            // 2,097,152 floats
    float* H1  = ws + 4194304;            // 32768 floats
    float* H2  = ws + 4227072;            // 32768 floats

    k_proj<<<dim3(B * N / NT), dim3(256), 0, stream>>>(X, W, a, Hp, H1, H2);
    k_agg<<<dim3(B * (N / IT)), dim3(256), 0, stream>>>(A, Hp, H1, H2, Hpr);
    k_out<<<dim3(B * N / R3), dim3(256), 0, stream>>>(Hpr, Wo, bo, out);
}

// Round 2
// 161.625 us; speedup vs baseline: 2.9601x; 2.9601x over previous
//
#include <hip/hip_runtime.h>

// Problem constants (fixed by setup_inputs)
constexpr int B = 4, N = 2048, I = 256, H = 4, D = 64, E = 256; // E = H*D

typedef __bf16 bf16x8 __attribute__((ext_vector_type(8)));
typedef float f32x4 __attribute__((ext_vector_type(4)));
typedef unsigned short us8 __attribute__((ext_vector_type(8)));

__device__ __forceinline__ unsigned short f2bf(float f) {
    unsigned u = __builtin_bit_cast(unsigned, f);
    u = (u + 0x7FFFu + ((u >> 16) & 1u)) >> 16;  // RNE
    return (unsigned short)u;
}

// ---------------- Kernel 1: per-head projection + H1/H2 + HpT(bf16) ----------------
// HpT[b][h][d][n] = bf16( sum_i X[b][n][i] * W[h][i][d] )
// H1[b][h][n] = dot(Hp, a[h,0:D]);  H2 with a[h,D:2D]   (fp32 exact)
constexpr int NT = 8; // nodes per block

__global__ __launch_bounds__(256) void k_proj(const float* __restrict__ X,
                                              const float* __restrict__ W,
                                              const float* __restrict__ a,
                                              unsigned short* __restrict__ HpT,
                                              float* __restrict__ H1,
                                              float* __restrict__ H2) {
    int blk = blockIdx.x;
    int b = blk / (N / NT);
    int n0 = (blk % (N / NT)) * NT;
    int t = threadIdx.x;
    int h = t >> 6, d = t & 63;

    __shared__ float Xs[NT][I]; // 8 KB

    const float4* Xr = (const float4*)(X + ((size_t)b * N + n0) * I);
    #pragma unroll
    for (int k = 0; k < (NT * I / 4) / 256; ++k) { // 2 iters
        int v = t + 256 * k;
        ((float4*)&Xs[0][0])[v] = Xr[v];
    }
    __syncthreads();

    float acc[NT];
    #pragma unroll
    for (int nn = 0; nn < NT; ++nn) acc[nn] = 0.f;

    const float* Wp = W + (size_t)h * I * D + d;
    #pragma unroll 2
    for (int i4 = 0; i4 < I; i4 += 4) {
        float w0 = Wp[(size_t)(i4 + 0) * D];
        float w1 = Wp[(size_t)(i4 + 1) * D];
        float w2 = Wp[(size_t)(i4 + 2) * D];
        float w3 = Wp[(size_t)(i4 + 3) * D];
        #pragma unroll
        for (int nn = 0; nn < NT; ++nn) {
            float4 x = *(const float4*)&Xs[nn][i4];
            acc[nn] += x.x * w0 + x.y * w1 + x.z * w2 + x.w * w3;
        }
    }

    float a1 = a[h * (2 * D) + d];
    float a2 = a[h * (2 * D) + D + d];

    #pragma unroll
    for (int nn = 0; nn < NT; ++nn) {
        float v1 = acc[nn] * a1;
        float v2 = acc[nn] * a2;
        #pragma unroll
        for (int off = 32; off > 0; off >>= 1) {
            v1 += __shfl_down(v1, off, 64);
            v2 += __shfl_down(v2, off, 64);
        }
        if (d == 0) {
            H1[(size_t)(b * H + h) * N + (n0 + nn)] = v1;
            H2[(size_t)(b * H + h) * N + (n0 + nn)] = v2;
        }
    }

    // transposed bf16 store: 8 consecutive n per thread at row d
    us8 o;
    #pragma unroll
    for (int nn = 0; nn < NT; ++nn) o[nn] = f2bf(acc[nn]);
    *(us8*)&HpT[((size_t)(b * H + h) * D + d) * N + n0] = o;
}

// ---------------- Kernel 2: head-softmax weights + MFMA aggregation ----------------
// w[h](i,j) = softmax over h of lrelu(H1[h,i]+H2[h,j]) if A[i,j]>0 else 0.25
// part[js][b][h][i][d] = sum_{j in split js} w[h](i,j) * Hp[b][h][j][d]
constexpr int IT = 16;    // i rows per block (one m-fragment)
constexpr int JSTEP = 32; // K per MFMA step
constexpr int JSPL = 2;   // j-range splits
constexpr int PART = B * H * N * D; // elements per partial buffer

__global__ __launch_bounds__(256) void k_agg(const int* __restrict__ A,
                                             const float* __restrict__ H1,
                                             const float* __restrict__ H2,
                                             const unsigned short* __restrict__ HpT,
                                             float* __restrict__ part) {
    int bid = blockIdx.x;
    int js = bid % JSPL;
    int it = (bid / JSPL) % (N / IT);
    int b  = bid / (JSPL * (N / IT));
    int i0 = it * IT;
    int jbase = js * (N / JSPL);
    int t = threadIdx.x;
    int h = t >> 6, l = t & 63;

    // weights in A-fragment-contiguous layout: [h][g=j>>3][i][e=j&7], 16B chunks
    __shared__ unsigned short wA[H * 4 * IT * 8]; // 4 KB

    // H1 values this thread needs are fixed: i = (t>>5) + 8r
    float h1r[2][H];
    #pragma unroll
    for (int r = 0; r < 2; ++r) {
        int i = (t >> 5) + 8 * r;
        #pragma unroll
        for (int hh = 0; hh < H; ++hh)
            h1r[r][hh] = H1[(size_t)(b * H + hh) * N + i0 + i];
    }

    f32x4 acc[4] = {}; // n-tiles of 16: d = (l&15) + 16*nt

    const int* Ab = A + (size_t)b * N * N;
    const float* H2b = H2 + (size_t)b * H * N;
    const unsigned short* Hpb = HpT + ((size_t)(b * H + h) * D) * N;

    for (int s = 0; s < (N / JSPL) / JSTEP; ++s) { // 32 steps
        int j0 = jbase + s * JSTEP;
        int j = t & 31;

        __syncthreads(); // prev Phase B done reading wA

        // ---- Phase A ----
        float h2v0 = H2b[0 * N + j0 + j];
        float h2v1 = H2b[1 * N + j0 + j];
        float h2v2 = H2b[2 * N + j0 + j];
        float h2v3 = H2b[3 * N + j0 + j];
        #pragma unroll
        for (int r = 0; r < 2; ++r) {
            int i = (t >> 5) + 8 * r;
            int aij = Ab[(size_t)(i0 + i) * N + j0 + j];
            float w0, w1, w2, w3;
            if (aij > 0) {
                float s0 = h1r[r][0] + h2v0;
                float s1 = h1r[r][1] + h2v1;
                float s2 = h1r[r][2] + h2v2;
                float s3 = h1r[r][3] + h2v3;
                s0 = fmaxf(s0, 0.2f * s0); // leaky relu
                s1 = fmaxf(s1, 0.2f * s1);
                s2 = fmaxf(s2, 0.2f * s2);
                s3 = fmaxf(s3, 0.2f * s3);
                float m = fmaxf(fmaxf(s0, s1), fmaxf(s2, s3));
                float e0 = __expf(s0 - m);
                float e1 = __expf(s1 - m);
                float e2 = __expf(s2 - m);
                float e3 = __expf(s3 - m);
                float zi = __builtin_amdgcn_rcpf(e0 + e1 + e2 + e3);
                w0 = e0 * zi; w1 = e1 * zi; w2 = e2 * zi; w3 = e3 * zi;
            } else {
                w0 = w1 = w2 = w3 = 0.25f;
            }
            int base = ((j >> 3) * IT + i) * 8 + (j & 7);
            wA[0 * 512 + base] = f2bf(w0);
            wA[1 * 512 + base] = f2bf(w1);
            wA[2 * 512 + base] = f2bf(w2);
            wA[3 * 512 + base] = f2bf(w3);
        }
        __syncthreads();

        // ---- Phase B: MFMA  C[i][d] += w[i][j] * Hp[j][d] ----
        // A-frag: lane l = row (l&15), k = (l>>4)*8+e  -> conflict-free b128
        bf16x8 af = *(const bf16x8*)&wA[(size_t)h * 512 + (((l >> 4) * IT) + (l & 15)) * 8];
        #pragma unroll
        for (int nt = 0; nt < 4; ++nt) {
            // B-frag: lane l = col d=(l&15)+16nt, k contiguous from HpT[d][j0+(l>>4)*8]
            us8 braw = *(const us8*)(Hpb + (size_t)((l & 15) + 16 * nt) * N + j0 + (l >> 4) * 8);
            bf16x8 bfr = __builtin_bit_cast(bf16x8, braw);
            acc[nt] = __builtin_amdgcn_mfma_f32_16x16x32_bf16(af, bfr, acc[nt], 0, 0, 0);
        }
    }

    // C/D layout: col = l&15 (+16*nt), row = (l>>4)*4 + r
    float* op = part + (size_t)js * PART + ((size_t)(b * H + h) * N + i0) * D + (l & 15);
    #pragma unroll
    for (int nt = 0; nt < 4; ++nt) {
        #pragma unroll
        for (int r = 0; r < 4; ++r) {
            int i = (l >> 4) * 4 + r;
            op[(size_t)i * D + 16 * nt] = acc[nt][r];
        }
    }
}

// ---------------- Kernel 3: out = (part0+part1) @ W_out^T + b_out ----------------
constexpr int R3 = 16; // rows per block
constexpr int ET = 32; // e' tile

__global__ __launch_bounds__(256) void k_out(const float* __restrict__ p0,
                                             const float* __restrict__ p1,
                                             const float* __restrict__ Wo,
                                             const float* __restrict__ bo,
                                             float* __restrict__ out) {
    int row0 = blockIdx.x * R3;
    int t = threadIdx.x;

    __shared__ float Rs[R3][E];       // 16 KB
    __shared__ float WT[ET][E + 1];   // 32.1 KB

    const float4* s0 = (const float4*)(p0 + (size_t)row0 * E);
    const float4* s1 = (const float4*)(p1 + (size_t)row0 * E);
    #pragma unroll
    for (int k = 0; k < (R3 * E / 4) / 256; ++k) { // 4
        int v = t + 256 * k;
        float4 x = s0[v], y = s1[v];
        x.x += y.x; x.y += y.y; x.z += y.z; x.w += y.w;
        ((float4*)&Rs[0][0])[v] = x;
    }

    float acc[R3];
    float bias = bo[t];
    #pragma unroll
    for (int i = 0; i < R3; ++i) acc[i] = bias;

    for (int et = 0; et < E / ET; ++et) { // 8 tiles
        __syncthreads();
        int c_l = t & 31;
        int rbase = t >> 5;
        #pragma unroll 8
        for (int k = 0; k < 32; ++k) {
            int r = rbase + 8 * k;
            WT[c_l][r] = Wo[(size_t)r * E + et * ET + c_l];
        }
        __syncthreads();

        #pragma unroll 4
        for (int cg = 0; cg < ET / 4; ++cg) {
            float w0 = WT[cg * 4 + 0][t];
            float w1 = WT[cg * 4 + 1][t];
            float w2 = WT[cg * 4 + 2][t];
            float w3 = WT[cg * 4 + 3][t];
            #pragma unroll
            for (int i = 0; i < R3; ++i) {
                float4 rv = *(const float4*)&Rs[i][et * ET + cg * 4];
                acc[i] += rv.x * w0 + rv.y * w1 + rv.z * w2 + rv.w * w3;
            }
        }
    }

    #pragma unroll
    for (int i = 0; i < R3; ++i) {
        out[(size_t)(row0 + i) * E + t] = acc[i];
    }
}

extern "C" void kernel_launch(void* const* d_in, const int* in_sizes, int n_in,
                              void* d_out, int out_size, void* d_ws, size_t ws_size,
                              hipStream_t stream) {
    const float* X  = (const float*)d_in[0];
    const int*   A  = (const int*)d_in[1];
    const float* W  = (const float*)d_in[2];
    const float* a  = (const float*)d_in[3];
    const float* Wo = (const float*)d_in[4];
    const float* bo = (const float*)d_in[5];
    float* out = (float*)d_out;

    float* ws   = (float*)d_ws;
    float* part = ws;                         // JSPL * B*H*N*D floats = 16 MB
    float* H1   = ws + (size_t)JSPL * PART;   // 32768 floats
    float* H2   = H1 + B * H * N;             // 32768 floats
    unsigned short* HpT = (unsigned short*)(H2 + B * H * N); // B*H*D*N bf16 = 4 MB

    k_proj<<<dim3(B * N / NT), dim3(256), 0, stream>>>(X, W, a, HpT, H1, H2);
    k_agg<<<dim3(B * (N / IT) * JSPL), dim3(256), 0, stream>>>(A, H1, H2, HpT, part);
    k_out<<<dim3(B * N / R3), dim3(256), 0, stream>>>(part, part + PART, Wo, bo, out);
}